// Round 9
// baseline (118.769 us; speedup 1.0000x reference)
//
#include <hip/hip_runtime.h>
#include <stdint.h>

// ---------------------------------------------------------------------------
// B=2048, F0=40, D=32, LAYER0=LAYER1=128.  Rows r=b*32+d (65536).
//   phase0: h0[r,s] = relu(sum_{i<40,j<40} X[r,i]X[r,j] W0[i,j,s] + b0[s])
//   phase1: d1[r,s] = relu(sum_{i<40,j<64} X[r,i]NH[r,j] W1[i,j,s] + b1[s])
//   out[b,0:64] = sum_d h0[:,64:128]; out[b,64:192] = sum_d d1
//
// Round-18: FAT WAVES -- restore A-frag reuse, halve per-SIMD VALU.
// r10-r17 invariant: MfmaUtil 42-48 + VALUBusy 31-36 + ~20 idle; pipes are
// ADDITIVE in this family (8 scheduling rounds all <±4%).  So shrink VALU:
// r15's 32x32 wave owned ONE 32-col tile -> an A-pair (8 pk_mul) fed only
// 2 MFMAs (4 pk/MFMA, 4x worse than r12's 16x16 with 4-col reuse), and the
// A-build repeats per wave (4 waves/SIMD).  Fix: 8 waves of 64r x 64c
// (512 thr, 1 block/CU, 2 waves/SIMD): per half-tile one A-pair (8 pk_mul)
// + 2 bv ds_read feed 4 MFMAs on 4 independent acc chains -> 2 pk/MFMA and
// half the waves -> per-SIMD VALU ~halves; MFMA floor unchanged (57K cyc).
// Registers: acc 4xf32x16 = 64 AGPR + arch ~60 (proven envelope).
// Schedule: r16 counted-vmcnt periods (PERIOD=2 tiles, triple buffer, raw
// s_barrier, steady-state vmcnt(2) since stage = 2 gl_lds16 per thread),
// setprio around MFMA cluster.  No r17 rotation (null result, costs regs).
// Carried: identity-DMA W layout [sq][kh][lane][oct] (conflict-free
// lane-linear b128), symmetrized-triangular W0 (30 tiles), fp16 datapath,
// phase-seam __syncthreads().
// ---------------------------------------------------------------------------

typedef __attribute__((ext_vector_type(8))) _Float16 half8;
typedef __attribute__((ext_vector_type(2))) _Float16 half2v;
typedef __attribute__((ext_vector_type(16))) float f32x16;

#define T0 30        // phase0 tiles after triangular drop
#define T1 80        // phase1 tiles
#define WBUF 8192    // halfwords per Wb buffer (2 tiles x 4096)

// phase-0 triangular schedule: jc blocks of sizes 2,4,6,8,10 (starts 0,2,6,12,20)
__host__ __device__ constexpr int ic0_of(int t) {
    return (t < 2) ? t : (t < 6) ? (t - 2) : (t < 12) ? (t - 6)
         : (t < 20) ? (t - 12) : (t - 20);
}
__host__ __device__ constexpr int jc0_of(int t) {
    return (t < 2) ? 0 : (t < 6) ? 1 : (t < 12) ? 2 : (t < 20) ? 3 : 4;
}

__device__ __forceinline__ unsigned short f2h(float f) {   // v_cvt_f16_f32, RNE
    return __builtin_bit_cast(unsigned short, (_Float16)f);
}
// async global->LDS DMA, 16 B/lane.  lds dest = (wave-uniform base) + lane*16.
__device__ __forceinline__ void gl_lds16(const unsigned short* g, unsigned short* l) {
    __builtin_amdgcn_global_load_lds(
        (const __attribute__((address_space(1))) unsigned int*)g,
        (__attribute__((address_space(3))) unsigned int*)l,
        16, 0, 0);
}
// A-fragment: broadcast x-scalar (both halves of xs) times 8 packed j-values.
__device__ __forceinline__ uint4 avmul(half2v xs, uint4 jv) {
    uint4 r;
    r.x = __builtin_bit_cast(unsigned int, (half2v)(xs * __builtin_bit_cast(half2v, jv.x)));
    r.y = __builtin_bit_cast(unsigned int, (half2v)(xs * __builtin_bit_cast(half2v, jv.y)));
    r.z = __builtin_bit_cast(unsigned int, (half2v)(xs * __builtin_bit_cast(half2v, jv.z)));
    r.w = __builtin_bit_cast(unsigned int, (half2v)(xs * __builtin_bit_cast(half2v, jv.w)));
    return r;
}

// ---------------------------------------------------------------------------
// Permute W -> Wp[t][ pos = sq*1024 + kh*512 + lane*8 + e ]:
//   s = sq*32 + (lane&31), hb = lane>>5, k = kh*16 + hb*8 + e,
//   i = ic*4 + kh*2 + hb, j = jc*8 + e.
// Exactly the 32x32x16 B-fragment read order (16B/lane, lane-linear) ->
// conflict-free ds_read_b128 AND identity global_load_lds staging.
// Phase0: symmetrized triangular Wsym.  110 blocks x 256 threads.
// ---------------------------------------------------------------------------
__global__ void permute_w_both(const float* __restrict__ W0, const float* __restrict__ W1,
                               unsigned short* __restrict__ Wp0, unsigned short* __restrict__ Wp1)
{
    const int t = blockIdx.x;
    const int tid = threadIdx.x;
    unsigned short outv[16];
    unsigned short* dst;
    if (t < T0) {
        const int ic = ic0_of(t), jc = jc0_of(t);
        #pragma unroll
        for (int q = 0; q < 16; ++q) {
            int pos  = tid * 16 + q;
            int e    = pos & 7, lane = (pos >> 3) & 63;
            int kh   = (pos >> 9) & 1, sq = pos >> 10;
            int s    = sq * 32 + (lane & 31);
            int i    = ic * 4 + kh * 2 + (lane >> 5);
            int j    = jc * 8 + e;
            float v = 0.0f;                                   // i>j: folded into (j,i)
            if (i < j)       v = W0[((size_t)(i * 40 + j)) * 128 + s]
                               + W0[((size_t)(j * 40 + i)) * 128 + s];
            else if (i == j) v = W0[((size_t)(i * 40 + i)) * 128 + s];
            outv[q] = f2h(v);
        }
        dst = Wp0 + (size_t)t * 4096 + tid * 16;
    } else {
        const int tt = t - T0;
        const int jc = tt / 10, ic = tt % 10;
        #pragma unroll
        for (int q = 0; q < 16; ++q) {
            int pos  = tid * 16 + q;
            int e    = pos & 7, lane = (pos >> 3) & 63;
            int kh   = (pos >> 9) & 1, sq = pos >> 10;
            int s    = sq * 32 + (lane & 31);
            int i    = ic * 4 + kh * 2 + (lane >> 5);
            int j    = jc * 8 + e;
            outv[q] = f2h(W1[((size_t)(i * 64 + j)) * 128 + s]);
        }
        dst = Wp1 + (size_t)tt * 4096 + tid * 16;
    }
    *(uint4*)dst       = *(const uint4*)outv;
    *(uint4*)(dst + 8) = *(const uint4*)(outv + 8);
}

// One GEMM phase.  8 waves: rt = wv>>1 (64 rows), sh = wv&1 (64 cols = col
// tiles sq = sh*2, sh*2+1).  Per half-tile: 2 bv ds_read_b128 + 8 pk_mul
// (one A-pair) + 4 MFMA 32x32x16 on 4 independent acc chains.  PERIOD=2
// tiles; Wb triple-buffered; one raw barrier per period; steady-state
// vmcnt(2) (stage = 2 gl_lds16/thread; never drains mid-loop).
template<int T, int PHASE>
__device__ __forceinline__ void gemm_phase(
    const unsigned short* __restrict__ Wp,   // [T][4096] fp16, global, read-order layout
    const unsigned short* __restrict__ Jl,   // LDS j-source (Xl or NH)
    int jstride,                             // row stride of Jl in elems
    const unsigned int xk[2][10],            // [kh][ic]: X[row0,i]|X[row1,i]<<16, i=ic*4+kh*2+hb
    unsigned short* Wb,                      // LDS W TRIPLE buffer [3][WBUF]
    f32x16 acc[2][2], int tid)
{
    const int lane = tid & 63;
    const int wv = tid >> 6;                 // wave id 0..7
    const int rt = wv >> 1;                  // row group (64 rows)
    const int sh = wv & 1;                   // col group (64 cols)
    const int c31 = lane & 31;

    const unsigned short* jbase0 = Jl + (rt * 64 + c31) * jstride;
    const unsigned short* jbase1 = jbase0 + 32 * jstride;
    // conflict-free bv base: col tiles sq = sh*2 (+0) and sh*2+1 (+1024)
    const unsigned short* brd = Wb + sh * 2048 + lane * 8;
    // DMA: 512 thr x 16B = half a 2-tile stage -> 2 calls per stage.
    // Identity layout: per-thread offset tid*8 halfwords (+4096 for call 2).
    const unsigned short* gsrc = Wp + tid * 8;
    unsigned short* ldst = Wb + tid * 8;

    auto stage = [&](int k) {   // stage period k (tiles 2k,2k+1) -> buf k%3
        gl_lds16(gsrc + (size_t)k * WBUF,        ldst + (k % 3) * WBUF);
        gl_lds16(gsrc + (size_t)k * WBUF + 4096, ldst + (k % 3) * WBUF + 4096);
    };

    constexpr int NP = T / 2;
    stage(0);
    stage(1);

    uint4 jv0, jv1;              // j-octet for row-tile 0 / 1
    #pragma unroll
    for (int p = 0; p < NP; ++p) {
        // stage(p) landed?  FIFO vmcnt: <=2 outstanding => only stage(p+1)'s
        // two loads may remain in flight.  Last period: drain fully.
        if (p == NP - 1) asm volatile("s_waitcnt vmcnt(0)" ::: "memory");
        else             asm volatile("s_waitcnt vmcnt(2)" ::: "memory");
        __builtin_amdgcn_sched_barrier(0);
        __builtin_amdgcn_s_barrier();        // raw: no vmcnt(0) drain
        __builtin_amdgcn_sched_barrier(0);
        if (p + 2 < NP) stage(p + 2);        // into buf freed by this barrier
        __builtin_amdgcn_sched_barrier(0);

        const unsigned short* bper = brd + (p % 3) * WBUF;
        #pragma unroll
        for (int u = 0; u < 2; ++u) {
            const int t  = p * 2 + u;                    // compile-time
            const int ic = (PHASE == 0) ? ic0_of(t) : (t % 10);
            const int jc = (PHASE == 0) ? jc0_of(t) : (t / 10);
            const bool rl = (t == 0) ||
                (jc != ((PHASE == 0) ? jc0_of(t - 1) : ((t - 1) / 10)));
            if (rl) {                                    // jv reload (jc changed)
                jv0 = *(const uint4*)(jbase0 + jc * 8);
                jv1 = *(const uint4*)(jbase1 + jc * 8);
            }
            __builtin_amdgcn_s_setprio(1);               // T5: favor MFMA cluster
            #pragma unroll
            for (int kh = 0; kh < 2; ++kh) {             // K16 halves of the K32 tile
                uint4 bv0 = *(const uint4*)(bper + u * 4096 + kh * 512);
                uint4 bv1 = *(const uint4*)(bper + u * 4096 + kh * 512 + 1024);
                half2v xp = __builtin_bit_cast(half2v, xk[kh][ic]);
                half2v x0 = {xp[0], xp[0]};              // row-tile 0 x-scalar
                half2v x1 = {xp[1], xp[1]};              // row-tile 1 x-scalar
                uint4 av0 = avmul(x0, jv0);              // 8 pk_mul feed 4 MFMA
                uint4 av1 = avmul(x1, jv1);
                acc[0][0] = __builtin_amdgcn_mfma_f32_32x32x16_f16(
                    __builtin_bit_cast(half8, av0),
                    __builtin_bit_cast(half8, bv0), acc[0][0], 0, 0, 0);
                acc[0][1] = __builtin_amdgcn_mfma_f32_32x32x16_f16(
                    __builtin_bit_cast(half8, av0),
                    __builtin_bit_cast(half8, bv1), acc[0][1], 0, 0, 0);
                acc[1][0] = __builtin_amdgcn_mfma_f32_32x32x16_f16(
                    __builtin_bit_cast(half8, av1),
                    __builtin_bit_cast(half8, bv0), acc[1][0], 0, 0, 0);
                acc[1][1] = __builtin_amdgcn_mfma_f32_32x32x16_f16(
                    __builtin_bit_cast(half8, av1),
                    __builtin_bit_cast(half8, bv1), acc[1][1], 0, 0, 0);
            }
            __builtin_amdgcn_s_setprio(0);
        }
    }
    // loop exit: all DMAs drained (last period waited vmcnt(0)); callers
    // place a full __syncthreads() at phase seams.
}

__global__ __launch_bounds__(512, 2)
void fused_two_layer(const float* __restrict__ x,
                     const unsigned short* __restrict__ W0p,
                     const float* __restrict__ b0,
                     const unsigned short* __restrict__ W1p,
                     const float* __restrict__ b1,
                     float* __restrict__ out)
{
    __shared__ __align__(16) unsigned short Xl[256 * 40];   // 20.0 KB
    __shared__ __align__(16) unsigned short NH[256 * 72];   // 36.9 KB (144B rows)
    __shared__ __align__(16) unsigned short Wb[3 * WBUF];   // 48.0 KB W triple buf
    // total 104.9 KB -> 1 block/CU, 8 waves = 2 waves/SIMD

    const int tid  = threadIdx.x;
    const int lane = tid & 63;
    const int wv   = tid >> 6;
    const int rt   = wv >> 1;           // row group (64 rows)
    const int sh   = wv & 1;            // col group (64 cols)
    const int c31  = lane & 31;
    const int hb   = lane >> 5;

    // ---- stage X: x[8b][i][d] fp32 -> Xl[(bl*32+d)*40 + i] fp16 (RNE) ----
    const float* xblk = x + (size_t)blockIdx.x * (8 * 40 * 32);
    #pragma unroll
    for (int k = 0; k < 20; ++k) {
        int f = 512 * k + tid;          // 0..10239, coalesced
        int bl = f / 1280, rem = f - bl * 1280;
        int i = rem >> 5, d = rem & 31;
        Xl[(bl * 32 + d) * 40 + i] = f2h(xblk[f]);
    }
    __syncthreads();

    // ---- preload this lane's i-scalars: i = ic*4 + kh*2 + hb, rows rt*64+c31
    //      (+32 for row-tile 1), packed lo/hi ----
    unsigned int xk[2][10];
    {
        const unsigned short* xr0 = Xl + (rt * 64 + c31) * 40;
        const unsigned short* xr1 = xr0 + 32 * 40;
        #pragma unroll
        for (int ic = 0; ic < 10; ++ic)
            #pragma unroll
            for (int kh = 0; kh < 2; ++kh) {
                unsigned int u0 = xr0[ic * 4 + kh * 2 + hb];
                unsigned int u1 = xr1[ic * 4 + kh * 2 + hb];
                xk[kh][ic] = u0 | (u1 << 16);
            }
    }

    f32x16 acc[2][2];
    #pragma unroll
    for (int a = 0; a < 2; ++a)
        #pragma unroll
        for (int b = 0; b < 2; ++b)
            #pragma unroll
            for (int rg = 0; rg < 16; ++rg) acc[a][b][rg] = 0.f;

    // ========== phase 0: 30 triangular tiles (Wsym), j from X ==========
    gemm_phase<T0, 0>(W0p, Xl, 40, xk, Wb, acc, tid);

    {   // epilogue 0: sh==0 (s<64) -> NH; sh==1 -> d-sum -> out[:,0:64]
        float bs[2] = { b0[sh * 64 + c31], b0[sh * 64 + 32 + c31] };
        if (sh == 0) {
            #pragma unroll
            for (int rtt = 0; rtt < 2; ++rtt)
                #pragma unroll
                for (int ct = 0; ct < 2; ++ct)
                    #pragma unroll
                    for (int rg = 0; rg < 16; ++rg) {
                        int row = rt * 64 + rtt * 32 + (rg & 3) + 8 * (rg >> 2) + 4 * hb;
                        NH[row * 72 + ct * 32 + c31] =
                            f2h(fmaxf(acc[rtt][ct][rg] + bs[ct], 0.0f));
                    }
        } else {
            #pragma unroll
            for (int rtt = 0; rtt < 2; ++rtt) {
                int bb = blockIdx.x * 8 + rt * 2 + rtt;   // 32-row tile == one batch
                #pragma unroll
                for (int ct = 0; ct < 2; ++ct) {
                    float s = 0.f;
                    #pragma unroll
                    for (int rg = 0; rg < 16; ++rg)
                        s += fmaxf(acc[rtt][ct][rg] + bs[ct], 0.0f);
                    s += __shfl_xor(s, 32, 64);  // add other hb's 16 rows
                    if (lane < 32)
                        out[(size_t)bb * 192 + ct * 32 + c31] = s;   // col = s-64
                }
            }
        }
    }
    __syncthreads();   // NH visible to all; drains vmcnt so phase-1 counting
                       // starts clean

    #pragma unroll
    for (int a = 0; a < 2; ++a)
        #pragma unroll
        for (int b = 0; b < 2; ++b)
            #pragma unroll
            for (int rg = 0; rg < 16; ++rg) acc[a][b][rg] = 0.f;

    // ========== phase 1: 80 tiles, j from NH ==========
    gemm_phase<T1, 1>(W1p, NH, 72, xk, Wb, acc, tid);

    {   // epilogue 1: bias+relu; d-sum -> out[:, 64:192]
        float bs[2] = { b1[sh * 64 + c31], b1[sh * 64 + 32 + c31] };
        #pragma unroll
        for (int rtt = 0; rtt < 2; ++rtt) {
            int bb = blockIdx.x * 8 + rt * 2 + rtt;
            #pragma unroll
            for (int ct = 0; ct < 2; ++ct) {
                float s = 0.f;
                #pragma unroll
                for (int rg = 0; rg < 16; ++rg)
                    s += fmaxf(acc[rtt][ct][rg] + bs[ct], 0.0f);
                s += __shfl_xor(s, 32, 64);
                if (lane < 32)
                    out[(size_t)bb * 192 + 64 + sh * 64 + ct * 32 + c31] = s;
            }
        }
    }
}

extern "C" void kernel_launch(void* const* d_in, const int* in_sizes, int n_in,
                              void* d_out, int out_size, void* d_ws, size_t ws_size,
                              hipStream_t stream) {
    const float* x  = (const float*)d_in[0];   // [2048][40][32]
    const float* W0 = (const float*)d_in[1];   // [40][40][128]
    const float* b0 = (const float*)d_in[2];   // [128]
    const float* W1 = (const float*)d_in[3];   // [40][64][128]
    const float* b1 = (const float*)d_in[4];   // [128]
    float* out = (float*)d_out;                // [2048][192]

    unsigned short* W0p = (unsigned short*)d_ws;                          // T0*8192 = 245760 B
    unsigned short* W1p = (unsigned short*)((char*)d_ws + T0 * 4096 * 2); // T1*8192 = 655360 B

    permute_w_both<<<T0 + T1, 256, 0, stream>>>(W0, W1, W0p, W1p);
    fused_two_layer<<<256, 512, 0, stream>>>(x, W0p, b0, W1p, b1, out);
}